// Round 1
// baseline (14997.005 us; speedup 1.0000x reference)
//
#include <hip/hip_runtime.h>
#include <hip/hip_bf16.h>
#include <cstdint>
#include <cstddef>

// ---------------------------------------------------------------------------
// RANNet: 2-layer recurrent additive network, B=128 S=2048 D=H=256, fc head.
// Phases per time-chunk:  x->bf16  | GEMM preact L0 | rec L0 | GEMM preact L1
//                         | rec L1 (state only) ; then fc on final h2.
// bf16 MFMA 16x16x32 everywhere; fp32 h master carried in registers.
// ---------------------------------------------------------------------------

typedef __bf16 bf16;
typedef __bf16 bf16x8 __attribute__((ext_vector_type(8)));
typedef __bf16 bf16x4 __attribute__((ext_vector_type(4)));
typedef float  floatx4 __attribute__((ext_vector_type(4)));

#define B_   128
#define S_   2048
#define H_   256

__device__ __forceinline__ float sigmoidf_(float x) {
    float e = __expf(-x);
    return __builtin_amdgcn_rcpf(1.0f + e);
}

// ---------------------------------------------------------------------------
// Weight prep: concat + fp32->bf16 ( W*cat rows = [Wf;Wi;Wx], U*cat = [Uf;Ui] )
// fcWT = transpose(fcW) kept fp32 for the epilogue.
// ---------------------------------------------------------------------------
__global__ void prep_weights(
    const float* __restrict__ Wf0, const float* __restrict__ Wi0, const float* __restrict__ Wx0,
    const float* __restrict__ Wf1, const float* __restrict__ Wi1, const float* __restrict__ Wx1,
    const float* __restrict__ Uf0, const float* __restrict__ Ui0,
    const float* __restrict__ Uf1, const float* __restrict__ Ui1,
    const float* __restrict__ bf0, const float* __restrict__ bi0, const float* __restrict__ bx0,
    const float* __restrict__ bf1, const float* __restrict__ bi1, const float* __restrict__ bx1,
    const float* __restrict__ fcW,
    bf16* __restrict__ W0cat, bf16* __restrict__ W1cat,
    bf16* __restrict__ U0cat, bf16* __restrict__ U1cat,
    float* __restrict__ b0cat, float* __restrict__ b1cat, float* __restrict__ fcWT)
{
    int tid = blockIdx.x * blockDim.x + threadIdx.x;
    int nth = gridDim.x * blockDim.x;
    for (int idx = tid; idx < 768 * 256; idx += nth) {
        int r = idx >> 8, k = idx & 255, rr = r & 255;
        const float* s0 = (r < 256) ? Wf0 : ((r < 512) ? Wi0 : Wx0);
        const float* s1 = (r < 256) ? Wf1 : ((r < 512) ? Wi1 : Wx1);
        W0cat[idx] = (bf16)s0[rr * 256 + k];
        W1cat[idx] = (bf16)s1[rr * 256 + k];
    }
    for (int idx = tid; idx < 512 * 256; idx += nth) {
        int r = idx >> 8, k = idx & 255, rr = r & 255;
        U0cat[idx] = (bf16)((r < 256 ? Uf0 : Ui0)[rr * 256 + k]);
        U1cat[idx] = (bf16)((r < 256 ? Uf1 : Ui1)[rr * 256 + k]);
    }
    for (int idx = tid; idx < 768; idx += nth) {
        const float* s0 = (idx < 256) ? bf0 : ((idx < 512) ? bi0 : bx0);
        const float* s1 = (idx < 256) ? bf1 : ((idx < 512) ? bi1 : bx1);
        b0cat[idx] = s0[idx & 255];
        b1cat[idx] = s1[idx & 255];
    }
    for (int idx = tid; idx < 256 * 256; idx += nth) {
        int h = idx >> 8, o = idx & 255;
        fcWT[idx] = fcW[o * 256 + h];   // fcWT[h][o]
    }
}

// ---------------------------------------------------------------------------
// x (fp32, [B][S][D]) chunk -> xa (bf16, [T][B][D], t chunk-local)
// ---------------------------------------------------------------------------
__global__ void convert_x(const float* __restrict__ x, bf16* __restrict__ xa, int t0, int T)
{
    int tid = blockIdx.x * blockDim.x + threadIdx.x;   // T*128*64 threads
    int d4 = tid & 63;
    int b  = (tid >> 6) & 127;
    int t  = tid >> 13;
    if (t >= T) return;
    const float4* src = (const float4*)(x + ((size_t)b * S_ + t0 + t) * H_) + d4;
    float4 v = *src;
    bf16x4 o = { (bf16)v.x, (bf16)v.y, (bf16)v.z, (bf16)v.w };
    *((bf16x4*)(xa + ((size_t)t * B_ + b) * H_) + d4) = o;
}

// ---------------------------------------------------------------------------
// Pre-activation GEMM: out[M][768] = A[M][256] @ Wcat[768][256]^T + bias
// 128x128 tile, BK=32, 4 waves (2x2 of 64x64), bf16 MFMA 16x16x32.
// ---------------------------------------------------------------------------
__global__ __launch_bounds__(256) void gemm_preact(
    const bf16* __restrict__ A, const bf16* __restrict__ W,
    const float* __restrict__ bias, bf16* __restrict__ out, int M)
{
    __shared__ bf16 At[128 * 32];   // [row][k] 64B rows
    __shared__ bf16 Bt[128 * 32];
    int m0 = blockIdx.x * 128;
    int n0 = blockIdx.y * 128;
    int tid = threadIdx.x;
    int lane = tid & 63, wave = tid >> 6;
    int wm = (wave >> 1) * 64, wn = (wave & 1) * 64;
    int qm = lane & 15, qk = lane >> 4;
    floatx4 acc[4][4] = {};

    for (int k0 = 0; k0 < 256; k0 += 32) {
#pragma unroll
        for (int j = 0; j < 2; ++j) {
            int c = tid * 2 + j;            // 16B chunk id
            int row = c >> 2, kc = c & 3;
            *(bf16x8*)(At + c * 8) = *(const bf16x8*)(A + (size_t)(m0 + row) * 256 + k0 + kc * 8);
            *(bf16x8*)(Bt + c * 8) = *(const bf16x8*)(W + (size_t)(n0 + row) * 256 + k0 + kc * 8);
        }
        __syncthreads();
        bf16x8 af[4], bfr[4];
#pragma unroll
        for (int i = 0; i < 4; ++i) {
            af[i]  = *(const bf16x8*)(At + (wm + i * 16 + qm) * 32 + qk * 8);
            bfr[i] = *(const bf16x8*)(Bt + (wn + i * 16 + qm) * 32 + qk * 8);
        }
#pragma unroll
        for (int mi = 0; mi < 4; ++mi)
#pragma unroll
            for (int ni = 0; ni < 4; ++ni)
                acc[mi][ni] = __builtin_amdgcn_mfma_f32_16x16x32_bf16(af[mi], bfr[ni], acc[mi][ni], 0, 0, 0);
        __syncthreads();
    }
#pragma unroll
    for (int mi = 0; mi < 4; ++mi)
#pragma unroll
        for (int ni = 0; ni < 4; ++ni) {
            int c = n0 + wn + ni * 16 + qm;
            float bb = bias[c];
#pragma unroll
            for (int r = 0; r < 4; ++r) {
                int m = m0 + wm + mi * 16 + qk * 4 + r;
                out[(size_t)m * 768 + c] = (bf16)(acc[mi][ni][r] + bb);
            }
        }
}

// ---------------------------------------------------------------------------
// Recurrence: grid = 8 WGs x 16 batch, 512 thr (8 waves).
// waves 0-3: f-gates (Uf, cols 64w..64w+64); waves 4-7: i-gates (Ui).
// U B-fragments stationary in registers; h fp32 master in regs of waves 0-3;
// bf16 h copy in LDS (padded) for A-fragments.
// ---------------------------------------------------------------------------
__global__ __launch_bounds__(512) void rec_layer(
    const bf16* __restrict__ pre,   // [T][128][768]  (xf|xi|xp)
    bf16* __restrict__ hout,        // [T][128][256] or nullptr
    const bf16* __restrict__ Ucat,  // [512][256] = [Uf;Ui]
    float* __restrict__ hstate,     // [128][256] in/out
    int T, int store_h)
{
    __shared__ bf16  hbf[16 * 264];     // [b][256+8pad]
    __shared__ float ibuf[16 * 257];    // [b][256+1pad]
    int tid = threadIdx.x;
    int lane = tid & 63, wave = tid >> 6;
    int bbase = blockIdx.x * 16;
    int qm = lane & 15, qk = lane >> 4;
    bool fside = wave < 4;
    int cbase = (wave & 3) * 64;
    int urow = (fside ? 0 : 256) + cbase;

    // stationary B-fragments: Uf[nt][kt], lane holds U[row=n][k..k+8) (contig)
    bf16x8 Ufr[4][8];
#pragma unroll
    for (int nt = 0; nt < 4; ++nt)
#pragma unroll
        for (int kt = 0; kt < 8; ++kt)
            Ufr[nt][kt] = *(const bf16x8*)(Ucat + (size_t)(urow + nt * 16 + qm) * 256 + kt * 32 + qk * 8);

    {   // init LDS h from fp32 state
        int row = tid >> 5, c8 = (tid & 31) * 8;
        const float* hs = hstate + (size_t)(bbase + row) * 256 + c8;
        bf16* dst = hbf + row * 264 + c8;
#pragma unroll
        for (int j = 0; j < 8; ++j) dst[j] = (bf16)hs[j];
    }
    float hm[4][4];   // fp32 master, waves 0-3: (b=qk*4+r, c=cbase+nt*16+qm)
    if (fside) {
#pragma unroll
        for (int nt = 0; nt < 4; ++nt)
#pragma unroll
            for (int r = 0; r < 4; ++r)
                hm[nt][r] = hstate[(size_t)(bbase + qk * 4 + r) * 256 + cbase + nt * 16 + qm];
    }
    __syncthreads();

    const int gofs = fside ? 0 : 256;
    for (int t = 0; t < T; ++t) {
        const bf16* prow = pre + ((size_t)t * 128 + bbase) * 768;
        // prefetch gate preact (+ xp for f-side) for this step
        float gp[4][4], xp[4][4];
#pragma unroll
        for (int nt = 0; nt < 4; ++nt)
#pragma unroll
            for (int r = 0; r < 4; ++r) {
                int b = qk * 4 + r, c = cbase + nt * 16 + qm;
                gp[nt][r] = (float)prow[(size_t)b * 768 + gofs + c];
                if (fside) xp[nt][r] = (float)prow[(size_t)b * 768 + 512 + c];
            }
        // h @ U^T : k-major to keep A-frag liveness short
        floatx4 acc[4] = {};
#pragma unroll
        for (int kt = 0; kt < 8; ++kt) {
            bf16x8 a = *(const bf16x8*)(hbf + qm * 264 + kt * 32 + qk * 8);
#pragma unroll
            for (int nt = 0; nt < 4; ++nt)
                acc[nt] = __builtin_amdgcn_mfma_f32_16x16x32_bf16(a, Ufr[nt][kt], acc[nt], 0, 0, 0);
        }
        float gate[4][4];
#pragma unroll
        for (int nt = 0; nt < 4; ++nt)
#pragma unroll
            for (int r = 0; r < 4; ++r)
                gate[nt][r] = sigmoidf_(acc[nt][r] + gp[nt][r]);
        if (!fside) {
#pragma unroll
            for (int nt = 0; nt < 4; ++nt)
#pragma unroll
                for (int r = 0; r < 4; ++r)
                    ibuf[(qk * 4 + r) * 257 + cbase + nt * 16 + qm] = gate[nt][r];
        }
        __syncthreads();
        if (fside) {
#pragma unroll
            for (int nt = 0; nt < 4; ++nt)
#pragma unroll
                for (int r = 0; r < 4; ++r) {
                    float iv = ibuf[(qk * 4 + r) * 257 + cbase + nt * 16 + qm];
                    float h = gate[nt][r] * hm[nt][r] + iv * xp[nt][r];
                    hm[nt][r] = h;
                    hbf[(qk * 4 + r) * 264 + cbase + nt * 16 + qm] = (bf16)h;
                }
        }
        __syncthreads();
        if (store_h) {   // coalesced cooperative store of h_t (bf16)
            int row = tid >> 5, c8 = (tid & 31) * 8;
            bf16x8 v = *(const bf16x8*)(hbf + row * 264 + c8);
            *(bf16x8*)(hout + ((size_t)t * 128 + bbase + row) * 256 + c8) = v;
        }
    }
    if (fside) {
#pragma unroll
        for (int nt = 0; nt < 4; ++nt)
#pragma unroll
            for (int r = 0; r < 4; ++r)
                hstate[(size_t)(bbase + qk * 4 + r) * 256 + cbase + nt * 16 + qm] = hm[nt][r];
    }
}

// ---------------------------------------------------------------------------
// fc head: out[b][o] = fcb[o] + sum_h h2[b][h] * fcWT[h][o]   (all fp32)
// ---------------------------------------------------------------------------
__global__ void fc_head(const float* __restrict__ h2, const float* __restrict__ fcWT,
                        const float* __restrict__ fcb, float* __restrict__ out)
{
    int b = blockIdx.x, o = threadIdx.x;
    __shared__ float hrow[256];
    hrow[o] = h2[(size_t)b * 256 + o];
    __syncthreads();
    float acc = fcb[o];
#pragma unroll 8
    for (int h = 0; h < 256; ++h)
        acc = fmaf(hrow[h], fcWT[h * 256 + o], acc);
    out[(size_t)b * 256 + o] = acc;
}

// ---------------------------------------------------------------------------
extern "C" void kernel_launch(void* const* d_in, const int* in_sizes, int n_in,
                              void* d_out, int out_size, void* d_ws, size_t ws_size,
                              hipStream_t stream)
{
    (void)in_sizes; (void)n_in; (void)out_size;
    const float* x   = (const float*)d_in[0];
    const float* Wf0 = (const float*)d_in[1];
    const float* bf0 = (const float*)d_in[2];
    const float* Uf0 = (const float*)d_in[3];
    const float* Wi0 = (const float*)d_in[4];
    const float* bi0 = (const float*)d_in[5];
    const float* Ui0 = (const float*)d_in[6];
    const float* Wx0 = (const float*)d_in[7];
    const float* bx0 = (const float*)d_in[8];
    const float* Wf1 = (const float*)d_in[9];
    const float* bf1 = (const float*)d_in[10];
    const float* Uf1 = (const float*)d_in[11];
    const float* Wi1 = (const float*)d_in[12];
    const float* bi1 = (const float*)d_in[13];
    const float* Ui1 = (const float*)d_in[14];
    const float* Wx1 = (const float*)d_in[15];
    const float* bx1 = (const float*)d_in[16];
    const float* fcW = (const float*)d_in[17];
    const float* fcb = (const float*)d_in[18];

    char* p = (char*)d_ws;
    auto alloc = [&](size_t bytes) -> char* {
        char* r = p; p += (bytes + 255) & ~(size_t)255; return r;
    };
    bf16*  W0cat = (bf16*)alloc(768 * 256 * 2);
    bf16*  W1cat = (bf16*)alloc(768 * 256 * 2);
    bf16*  U0cat = (bf16*)alloc(512 * 256 * 2);
    bf16*  U1cat = (bf16*)alloc(512 * 256 * 2);
    float* b0cat = (float*)alloc(768 * 4);
    float* b1cat = (float*)alloc(768 * 4);
    float* fcWT  = (float*)alloc(256 * 256 * 4);
    float* h0s   = (float*)alloc(128 * 256 * 4);
    float* h1s   = (float*)alloc(128 * 256 * 4);
    size_t fixed = (size_t)(p - (char*)d_ws);

    // per-chunk bytes = T_c * 128 * 2 * (256 + 768 + 256 + 768) = T_c * 524288
    int T_c = 2048;
    while (T_c > 32 && fixed + (size_t)T_c * 524288 + 4096 > ws_size) T_c >>= 1;
    bf16* xa   = (bf16*)alloc((size_t)T_c * 128 * 256 * 2);
    bf16* pre0 = (bf16*)alloc((size_t)T_c * 128 * 768 * 2);
    bf16* h1b  = (bf16*)alloc((size_t)T_c * 128 * 256 * 2);
    bf16* pre1 = (bf16*)alloc((size_t)T_c * 128 * 768 * 2);

    hipMemsetAsync(h0s, 0, 128 * 256 * 4, stream);
    hipMemsetAsync(h1s, 0, 128 * 256 * 4, stream);

    prep_weights<<<512, 256, 0, stream>>>(Wf0, Wi0, Wx0, Wf1, Wi1, Wx1,
                                          Uf0, Ui0, Uf1, Ui1,
                                          bf0, bi0, bx0, bf1, bi1, bx1, fcW,
                                          W0cat, W1cat, U0cat, U1cat, b0cat, b1cat, fcWT);

    int NC = S_ / T_c;
    for (int c = 0; c < NC; ++c) {
        int t0 = c * T_c;
        convert_x<<<T_c * 32, 256, 0, stream>>>(x, xa, t0, T_c);
        gemm_preact<<<dim3(T_c, 6), 256, 0, stream>>>(xa, W0cat, b0cat, pre0, T_c * 128);
        rec_layer<<<8, 512, 0, stream>>>(pre0, h1b, U0cat, h0s, T_c, 1);
        gemm_preact<<<dim3(T_c, 6), 256, 0, stream>>>(h1b, W1cat, b1cat, pre1, T_c * 128);
        rec_layer<<<8, 512, 0, stream>>>(pre1, nullptr, U1cat, h1s, T_c, 0);
    }
    fc_head<<<128, 256, 0, stream>>>(h1s, fcWT, fcb, (float*)d_out);
}

// Round 2
// 5241.885 us; speedup vs baseline: 2.8610x; 2.8610x over previous
//
#include <hip/hip_runtime.h>
#include <hip/hip_bf16.h>
#include <cstdint>
#include <cstddef>

// ---------------------------------------------------------------------------
// RANNet: 2-layer recurrent additive network, B=128 S=2048 D=H=256, fc head.
// Round 2: latency-optimized recurrence.
//  - GEMM epilogue writes preacts f32 in rec-fragment order (coalesced 16B
//    loads in rec), with f/i pre-scaled by -log2(e).
//  - rec: each wave owns 32 h-columns and computes BOTH gates for them ->
//    no cross-wave gate exchange; double-buffered LDS h tile -> ONE barrier
//    per step; depth-1 software prefetch of next step's preacts.
// ---------------------------------------------------------------------------

typedef __bf16 bf16;
typedef __bf16 bf16x8 __attribute__((ext_vector_type(8)));
typedef __bf16 bf16x4 __attribute__((ext_vector_type(4)));
typedef float  floatx4 __attribute__((ext_vector_type(4)));

#define B_   128
#define S_   2048
#define H_   256
#define NEG_LOG2E -1.442695040888963f

// ---------------------------------------------------------------------------
// Weight prep: concat + fp32->bf16 ( W*cat rows = [Wf;Wi;Wx], U*cat = [Uf;Ui] )
// fcWT = transpose(fcW) kept fp32 for the epilogue.
// ---------------------------------------------------------------------------
__global__ void prep_weights(
    const float* __restrict__ Wf0, const float* __restrict__ Wi0, const float* __restrict__ Wx0,
    const float* __restrict__ Wf1, const float* __restrict__ Wi1, const float* __restrict__ Wx1,
    const float* __restrict__ Uf0, const float* __restrict__ Ui0,
    const float* __restrict__ Uf1, const float* __restrict__ Ui1,
    const float* __restrict__ bf0, const float* __restrict__ bi0, const float* __restrict__ bx0,
    const float* __restrict__ bf1, const float* __restrict__ bi1, const float* __restrict__ bx1,
    const float* __restrict__ fcW,
    bf16* __restrict__ W0cat, bf16* __restrict__ W1cat,
    bf16* __restrict__ U0cat, bf16* __restrict__ U1cat,
    float* __restrict__ b0cat, float* __restrict__ b1cat, float* __restrict__ fcWT)
{
    int tid = blockIdx.x * blockDim.x + threadIdx.x;
    int nth = gridDim.x * blockDim.x;
    for (int idx = tid; idx < 768 * 256; idx += nth) {
        int r = idx >> 8, k = idx & 255, rr = r & 255;
        const float* s0 = (r < 256) ? Wf0 : ((r < 512) ? Wi0 : Wx0);
        const float* s1 = (r < 256) ? Wf1 : ((r < 512) ? Wi1 : Wx1);
        W0cat[idx] = (bf16)s0[rr * 256 + k];
        W1cat[idx] = (bf16)s1[rr * 256 + k];
    }
    for (int idx = tid; idx < 512 * 256; idx += nth) {
        int r = idx >> 8, k = idx & 255, rr = r & 255;
        U0cat[idx] = (bf16)((r < 256 ? Uf0 : Ui0)[rr * 256 + k]);
        U1cat[idx] = (bf16)((r < 256 ? Uf1 : Ui1)[rr * 256 + k]);
    }
    for (int idx = tid; idx < 768; idx += nth) {
        const float* s0 = (idx < 256) ? bf0 : ((idx < 512) ? bi0 : bx0);
        const float* s1 = (idx < 256) ? bf1 : ((idx < 512) ? bi1 : bx1);
        b0cat[idx] = s0[idx & 255];
        b1cat[idx] = s1[idx & 255];
    }
    for (int idx = tid; idx < 256 * 256; idx += nth) {
        int h = idx >> 8, o = idx & 255;
        fcWT[idx] = fcW[o * 256 + h];   // fcWT[h][o]
    }
}

// ---------------------------------------------------------------------------
// x (fp32, [B][S][D]) chunk -> xa (bf16, [T][B][D], t chunk-local)
// ---------------------------------------------------------------------------
__global__ void convert_x(const float* __restrict__ x, bf16* __restrict__ xa, int t0, int T)
{
    int tid = blockIdx.x * blockDim.x + threadIdx.x;   // T*128*64 threads
    int d4 = tid & 63;
    int b  = (tid >> 6) & 127;
    int t  = tid >> 13;
    if (t >= T) return;
    const float4* src = (const float4*)(x + ((size_t)b * S_ + t0 + t) * H_) + d4;
    float4 v = *src;
    bf16x4 o = { (bf16)v.x, (bf16)v.y, (bf16)v.z, (bf16)v.w };
    *((bf16x4*)(xa + ((size_t)t * B_ + b) * H_) + d4) = o;
}

// ---------------------------------------------------------------------------
// Pre-activation GEMM: C[M][768] = A[M][256] @ Wcat[768][256]^T + bias,
// written f32 into rec-fragment order:
//   preP float offset = t*98304 + ((wg*8+wv)*6 + g*2+nt)*256 + qk*64 + qm*4 (+r)
// where t = chunk-local timestep (= blockIdx.x here since 128 rows == one t),
// b = m&127, wg=b>>4, qk=(b>>2)&3, r=b&3; c = gate col: g=c>>8, ch=c&255,
// wv=ch>>5, nt=(ch>>4)&1, qm=ch&15.  f/i (g<2) pre-scaled by -log2(e).
// ---------------------------------------------------------------------------
__global__ __launch_bounds__(256) void gemm_preact(
    const bf16* __restrict__ A, const bf16* __restrict__ W,
    const float* __restrict__ bias, float* __restrict__ preP)
{
    __shared__ bf16 At[128 * 32];   // [row][k] 64B rows
    __shared__ bf16 Bt[128 * 32];
    int m0 = blockIdx.x * 128;
    int n0 = blockIdx.y * 128;
    int tid = threadIdx.x;
    int lane = tid & 63, wave = tid >> 6;
    int wm = (wave >> 1) * 64, wn = (wave & 1) * 64;
    int qm = lane & 15, qk = lane >> 4;
    floatx4 acc[4][4] = {};

    for (int k0 = 0; k0 < 256; k0 += 32) {
#pragma unroll
        for (int j = 0; j < 2; ++j) {
            int c = tid * 2 + j;            // 16B chunk id
            int row = c >> 2, kc = c & 3;
            *(bf16x8*)(At + c * 8) = *(const bf16x8*)(A + (size_t)(m0 + row) * 256 + k0 + kc * 8);
            *(bf16x8*)(Bt + c * 8) = *(const bf16x8*)(W + (size_t)(n0 + row) * 256 + k0 + kc * 8);
        }
        __syncthreads();
        bf16x8 af[4], bfr[4];
#pragma unroll
        for (int i = 0; i < 4; ++i) {
            af[i]  = *(const bf16x8*)(At + (wm + i * 16 + qm) * 32 + qk * 8);
            bfr[i] = *(const bf16x8*)(Bt + (wn + i * 16 + qm) * 32 + qk * 8);
        }
#pragma unroll
        for (int mi = 0; mi < 4; ++mi)
#pragma unroll
            for (int ni = 0; ni < 4; ++ni)
                acc[mi][ni] = __builtin_amdgcn_mfma_f32_16x16x32_bf16(af[mi], bfr[ni], acc[mi][ni], 0, 0, 0);
        __syncthreads();
    }
    // epilogue: scatter 16B stores into rec-fragment layout
    int t = blockIdx.x;                       // 128 rows == exactly one timestep
#pragma unroll
    for (int mi = 0; mi < 4; ++mi) {
        int b = wm + mi * 16 + qk * 4;        // + r
        int wg = b >> 4;
#pragma unroll
        for (int ni = 0; ni < 4; ++ni) {
            int c = n0 + wn + ni * 16 + qm;
            int g = c >> 8, ch = c & 255, wv = ch >> 5, nt = (ch >> 4) & 1;
            float bb = bias[c];
            float4 v;
            float* vp = (float*)&v;
#pragma unroll
            for (int r = 0; r < 4; ++r) {
                float val = acc[mi][ni][r] + bb;
                vp[r] = (g < 2) ? NEG_LOG2E * val : val;
            }
            size_t off = (size_t)t * 98304 + (size_t)((wg * 8 + wv) * 6 + g * 2 + nt) * 256
                       + qk * 64 + qm * 4;
            *(float4*)(preP + off) = v;
        }
    }
}

// ---------------------------------------------------------------------------
// Recurrence: 8 WGs x 16 batch, 512 thr (8 waves). Wave w owns h-cols
// [32w, 32w+32) and computes BOTH f and i gates for them (no exchange).
// U kept as stationary register B-fragments (Uf+Ui = 128 VGPRs/lane).
// h: fp32 master in regs; bf16 copy in double-buffered LDS for A-fragments.
// One __syncthreads per step. Depth-1 prefetch of preacts (6x dwordx4).
// ---------------------------------------------------------------------------
__global__ __launch_bounds__(512) void rec_layer(
    const float* __restrict__ preP,  // [T][8wg][8wv][6 chunks][256 floats]
    bf16* __restrict__ hout,         // [T][128][256] bf16, or nullptr
    const bf16* __restrict__ Ucat,   // [512][256] = [Uf;Ui]
    float* __restrict__ hstate,      // [128][256] in/out
    int T)
{
    __shared__ bf16 hb[2][16 * 264];     // [buf][b][256+8pad]
    const int tid = threadIdx.x, lane = tid & 63, wave = tid >> 6;
    const int qm = lane & 15, qk = lane >> 4;
    const int wg = blockIdx.x, bbase = wg * 16, cb = wave * 32;

    // stationary U fragments (B-operand layout): row n = col index, k contig
    bf16x8 Ufr[2][8], Uir[2][8];
#pragma unroll
    for (int nt = 0; nt < 2; ++nt)
#pragma unroll
        for (int kt = 0; kt < 8; ++kt) {
            Ufr[nt][kt] = *(const bf16x8*)(Ucat + (size_t)(cb + nt * 16 + qm) * 256 + kt * 32 + qk * 8);
            Uir[nt][kt] = *(const bf16x8*)(Ucat + (size_t)(256 + cb + nt * 16 + qm) * 256 + kt * 32 + qk * 8);
        }
    {   // init LDS h (buf 0) from fp32 state
        int row = tid >> 5, c8 = (tid & 31) * 8;
        const float* hs = hstate + (size_t)(bbase + row) * 256 + c8;
        bf16x8 v;
#pragma unroll
        for (int j = 0; j < 8; ++j) v[j] = (bf16)hs[j];
        *(bf16x8*)(hb[0] + row * 264 + c8) = v;
    }
    float hm[2][4];   // fp32 master: (b = qk*4+r, c = cb+nt*16+qm)
#pragma unroll
    for (int nt = 0; nt < 2; ++nt)
#pragma unroll
        for (int r = 0; r < 4; ++r)
            hm[nt][r] = hstate[(size_t)(bbase + qk * 4 + r) * 256 + cb + nt * 16 + qm];
    __syncthreads();

    const float4* pw = (const float4*)preP + (size_t)(wg * 8 + wave) * 384 + lane;
#define PLD(dst, tt) { size_t o_ = (size_t)(tt) * 24576;                        \
        dst[0] = pw[o_];       dst[1] = pw[o_ + 64];  dst[2] = pw[o_ + 128];    \
        dst[3] = pw[o_ + 192]; dst[4] = pw[o_ + 256]; dst[5] = pw[o_ + 320]; }

    float4 bufA[6], bufB[6];
    PLD(bufA, 0);
    int cur = 0;

    auto step = [&](int t, int curb, const float4* p) {
        floatx4 accf[2] = {}, acci[2] = {};
        const bf16* hc = hb[curb];
#pragma unroll
        for (int kt = 0; kt < 8; ++kt) {
            bf16x8 a = *(const bf16x8*)(hc + qm * 264 + kt * 32 + qk * 8);
            accf[0] = __builtin_amdgcn_mfma_f32_16x16x32_bf16(a, Ufr[0][kt], accf[0], 0, 0, 0);
            accf[1] = __builtin_amdgcn_mfma_f32_16x16x32_bf16(a, Ufr[1][kt], accf[1], 0, 0, 0);
            acci[0] = __builtin_amdgcn_mfma_f32_16x16x32_bf16(a, Uir[0][kt], acci[0], 0, 0, 0);
            acci[1] = __builtin_amdgcn_mfma_f32_16x16x32_bf16(a, Uir[1][kt], acci[1], 0, 0, 0);
        }
        bf16* hn = hb[curb ^ 1];
#pragma unroll
        for (int nt = 0; nt < 2; ++nt)
#pragma unroll
            for (int r = 0; r < 4; ++r) {
                float pf = ((const float*)&p[nt])[r];        // chunk g*2+nt
                float pi = ((const float*)&p[2 + nt])[r];
                float px = ((const float*)&p[4 + nt])[r];
                // f = sigmoid(accf+xf) ; i = sigmoid(acci+xi); h = f*h + i*xp
                // = [h*(1+ei) + xp*(1+ef)] / [(1+ef)(1+ei)],  e* = exp2(-K*z)
                float ef = fminf(fmaf(accf[nt][r], NEG_LOG2E, pf), 80.0f);
                float ei = fminf(fmaf(acci[nt][r], NEG_LOG2E, pi), 80.0f);
                float A1 = 1.0f + __builtin_amdgcn_exp2f(ef);
                float B1 = 1.0f + __builtin_amdgcn_exp2f(ei);
                float N  = fmaf(hm[nt][r], B1, px * A1);
                float h  = N * __builtin_amdgcn_rcpf(A1 * B1);
                hm[nt][r] = h;
                hn[(qk * 4 + r) * 264 + cb + nt * 16 + qm] = (bf16)h;
            }
        __syncthreads();
        if (hout) {   // coalesced store of h_t from the just-written buffer
            int row = tid >> 5, c8 = (tid & 31) * 8;
            bf16x8 v = *(const bf16x8*)(hn + row * 264 + c8);
            *(bf16x8*)(hout + ((size_t)t * 128 + bbase + row) * 256 + c8) = v;
        }
    };

    for (int t = 0; t < T; t += 2) {          // T is even (power of two >= 32)
        PLD(bufB, t + 1);
        step(t, cur, bufA);  cur ^= 1;
        int t2 = (t + 2 < T) ? t + 2 : t;     // clamped dummy reload on last iter
        PLD(bufA, t2);
        step(t + 1, cur, bufB); cur ^= 1;
    }
#undef PLD
#pragma unroll
    for (int nt = 0; nt < 2; ++nt)
#pragma unroll
        for (int r = 0; r < 4; ++r)
            hstate[(size_t)(bbase + qk * 4 + r) * 256 + cb + nt * 16 + qm] = hm[nt][r];
}

// ---------------------------------------------------------------------------
// fc head: out[b][o] = fcb[o] + sum_h h2[b][h] * fcWT[h][o]   (all fp32)
// ---------------------------------------------------------------------------
__global__ void fc_head(const float* __restrict__ h2, const float* __restrict__ fcWT,
                        const float* __restrict__ fcb, float* __restrict__ out)
{
    int b = blockIdx.x, o = threadIdx.x;
    __shared__ float hrow[256];
    hrow[o] = h2[(size_t)b * 256 + o];
    __syncthreads();
    float acc = fcb[o];
#pragma unroll 8
    for (int h = 0; h < 256; ++h)
        acc = fmaf(hrow[h], fcWT[h * 256 + o], acc);
    out[(size_t)b * 256 + o] = acc;
}

// ---------------------------------------------------------------------------
extern "C" void kernel_launch(void* const* d_in, const int* in_sizes, int n_in,
                              void* d_out, int out_size, void* d_ws, size_t ws_size,
                              hipStream_t stream)
{
    (void)in_sizes; (void)n_in; (void)out_size;
    const float* x   = (const float*)d_in[0];
    const float* Wf0 = (const float*)d_in[1];
    const float* bf0 = (const float*)d_in[2];
    const float* Uf0 = (const float*)d_in[3];
    const float* Wi0 = (const float*)d_in[4];
    const float* bi0 = (const float*)d_in[5];
    const float* Ui0 = (const float*)d_in[6];
    const float* Wx0 = (const float*)d_in[7];
    const float* bx0 = (const float*)d_in[8];
    const float* Wf1 = (const float*)d_in[9];
    const float* bf1 = (const float*)d_in[10];
    const float* Uf1 = (const float*)d_in[11];
    const float* Wi1 = (const float*)d_in[12];
    const float* bi1 = (const float*)d_in[13];
    const float* Ui1 = (const float*)d_in[14];
    const float* Wx1 = (const float*)d_in[15];
    const float* bx1 = (const float*)d_in[16];
    const float* fcW = (const float*)d_in[17];
    const float* fcb = (const float*)d_in[18];

    char* p = (char*)d_ws;
    auto alloc = [&](size_t bytes) -> char* {
        char* r = p; p += (bytes + 255) & ~(size_t)255; return r;
    };
    bf16*  W0cat = (bf16*)alloc(768 * 256 * 2);
    bf16*  W1cat = (bf16*)alloc(768 * 256 * 2);
    bf16*  U0cat = (bf16*)alloc(512 * 256 * 2);
    bf16*  U1cat = (bf16*)alloc(512 * 256 * 2);
    float* b0cat = (float*)alloc(768 * 4);
    float* b1cat = (float*)alloc(768 * 4);
    float* fcWT  = (float*)alloc(256 * 256 * 4);
    float* h0s   = (float*)alloc(128 * 256 * 4);
    float* h1s   = (float*)alloc(128 * 256 * 4);
    size_t fixed = (size_t)(p - (char*)d_ws);

    // per-chunk bytes = T_c * (128*256*2 + 128*768*4 + 128*256*2 + 128*768*4)
    //                 = T_c * 917504
    int T_c = 2048;
    while (T_c > 32 && fixed + (size_t)T_c * 917504 + 4096 > ws_size) T_c >>= 1;
    bf16*  xa   = (bf16*)alloc((size_t)T_c * 128 * 256 * 2);
    float* pre0 = (float*)alloc((size_t)T_c * 128 * 768 * 4);
    bf16*  h1b  = (bf16*)alloc((size_t)T_c * 128 * 256 * 2);
    float* pre1 = (float*)alloc((size_t)T_c * 128 * 768 * 4);

    hipMemsetAsync(h0s, 0, 128 * 256 * 4, stream);
    hipMemsetAsync(h1s, 0, 128 * 256 * 4, stream);

    prep_weights<<<512, 256, 0, stream>>>(Wf0, Wi0, Wx0, Wf1, Wi1, Wx1,
                                          Uf0, Ui0, Uf1, Ui1,
                                          bf0, bi0, bx0, bf1, bi1, bx1, fcW,
                                          W0cat, W1cat, U0cat, U1cat, b0cat, b1cat, fcWT);

    int NC = S_ / T_c;
    for (int c = 0; c < NC; ++c) {
        int t0 = c * T_c;
        convert_x<<<T_c * 32, 256, 0, stream>>>(x, xa, t0, T_c);
        gemm_preact<<<dim3(T_c, 6), 256, 0, stream>>>(xa, W0cat, b0cat, pre0);
        rec_layer<<<8, 512, 0, stream>>>(pre0, h1b, U0cat, h0s, T_c);
        gemm_preact<<<dim3(T_c, 6), 256, 0, stream>>>(h1b, W1cat, b1cat, pre1);
        rec_layer<<<8, 512, 0, stream>>>(pre1, nullptr, U1cat, h1s, T_c);
    }
    fc_head<<<128, 256, 0, stream>>>(h1s, fcWT, fcb, (float*)d_out);
}